// Round 1
// 5818.884 us; speedup vs baseline: 1.0562x; 1.0562x over previous
//
#include <hip/hip_runtime.h>
#include <hip/hip_bf16.h>

#define TT 512
#define NB 1024

typedef float f32x4 __attribute__((ext_vector_type(4)));
typedef __bf16 bf16x8 __attribute__((ext_vector_type(8)));

// ---- workspace layout (bf16 elems). All matrices stored as A-fragments for
// the TRANSPOSED GEMM  C^T[feature][batch] = W^T @ act^T :
//   frag(mt, kt, lane, j) at ((mt*KT + kt)*512 + lane*8 + j)
//   value = W[kappa][16*mt + (lane&15)]
// For weights consuming register-resident activations (Whp, Wm, Whpost, Wr1):
//   kappa = 32*kt + 16*(j>>2) + 4*(lane>>4) + (j&3)  [pi-permutation: B-frag ==
//   accumulator contents of the producing stage]. For Wcp (consumes x):
//   kappa = 32*kt + 8*(lane>>4) + j (natural).
#define OFF_HP 0
#define OFF_CP 65536
#define OFF_M  81920
#define OFF_PO 212992
#define OFF_R1 278528
#define TOT    344064

__global__ __launch_bounds__(256) void pack_weights(
    const float* __restrict__ Whp, const float* __restrict__ Wm,
    const float* __restrict__ Wcp, const float* __restrict__ Whpost,
    const float* __restrict__ Wr1, __bf16* __restrict__ wsp) {
  int id = blockIdx.x * 256 + threadIdx.x;
  if (id >= TOT) return;
  int j = id & 7, lane = (id >> 3) & 63;
  int lq = lane >> 4, l15 = lane & 15;
  int rel, KT; const float* W; bool perm = true;
  if (id < OFF_CP)      { rel = id;          KT = 8;  W = Whp; }
  else if (id < OFF_M)  { rel = id - OFF_CP; KT = 2;  W = Wcp; perm = false; }
  else if (id < OFF_PO) { rel = id - OFF_M;  KT = 16; W = Wm; }
  else if (id < OFF_R1) { rel = id - OFF_PO; KT = 8;  W = Whpost; }
  else                  { rel = id - OFF_R1; KT = 8;  W = Wr1; }
  int ktm = rel >> 9;
  int kt = ktm % KT, mt = ktm / KT;
  int phi = 16 * mt + l15;
  int kk;
  if (perm) {
    int kb = (kt >= 8) ? kt - 8 : kt;          // only mesh has kt>=8
    kk = 32 * kb + 16 * (j >> 2) + 4 * lq + (j & 3);
    if (kt >= 8) kk += 256;                    // cp half of the concat
  } else {
    kk = 32 * kt + 8 * lq + j;
  }
  wsp[id] = (__bf16)W[kk * 256 + phi];
}

__device__ __forceinline__ float tanh_fast(float x) {
  float t = __expf(2.0f * x);
  return 1.0f - __fdividef(2.0f, t + 1.0f);
}

#define MFMA(a, b, c) __builtin_amdgcn_mfma_f32_16x16x32_bf16((a), (b), (c), 0, 0, 0)

// tanh + pack this wave's two accumulators into ONE B-fragment (kt = wv).
// Pure in-lane: B[wv][j] = tanh(acc[j>>2][j&3]). Conflict-free ds_write_b128.
__device__ __forceinline__ void pack2(__bf16* region, int wv, int lane,
                                      const f32x4& a0, const f32x4& a1) {
  bf16x8 f;
  #pragma unroll
  for (int r = 0; r < 4; ++r) {
    f[r]     = (__bf16)tanh_fast(a0[r]);
    f[4 + r] = (__bf16)tanh_fast(a1[r]);
  }
  *(bf16x8*)(region + wv * 512 + lane * 8) = f;
}

// Raw barrier: make LDS writes visible (lgkmcnt only) WITHOUT draining vmcnt.
// __syncthreads() would emit s_waitcnt vmcnt(0) before s_barrier, forcing the
// cross-barrier global prefetches (x, hp/po/r1 weight frags) to complete at
// every barrier. This keeps them in flight; the compiler still inserts the
// correct vmcnt waits before each load's first use.
__device__ __forceinline__ void barrier_lds() {
  asm volatile("s_waitcnt lgkmcnt(0)" ::: "memory");
  __builtin_amdgcn_s_barrier();
  asm volatile("" ::: "memory");
}

__global__ __launch_bounds__(512)
__attribute__((amdgpu_waves_per_eu(2, 2)))   // force 256-VGPR budget: wm MUST stay resident
void rnn_seq(
    const float* __restrict__ x, const __bf16* __restrict__ wsp,
    const float* __restrict__ bhp, const float* __restrict__ bcp,
    const float* __restrict__ bm, const float* __restrict__ bhpost,
    const float* __restrict__ br1, const float* __restrict__ Wr2,
    const float* __restrict__ br2, float* __restrict__ out) {
  __shared__ __align__(16) __bf16 hB[8 * 512];   // h state as B-frags
  __shared__ __align__(16) __bf16 mB[16 * 512];  // [hpB | cpB] for mesh
  __shared__ __align__(16) __bf16 uB[8 * 512];   // mesh output
  __shared__ float lb[6 * 256];                  // bhp,bcp,bm,bhpost,br1,Wr2
  __shared__ float outp[128];

  const int tid  = threadIdx.x;
  const int wv   = tid >> 6;      // 0..7, owns m-tiles 2wv, 2wv+1
  const int lane = tid & 63;
  const int lq   = lane >> 4, l15 = lane & 15;
  const int n0   = blockIdx.x * 16;
  const int mt0  = 2 * wv;

  if (tid < 256) {
    lb[0 * 256 + tid] = bhp[tid];
    lb[1 * 256 + tid] = bcp[tid];
    lb[2 * 256 + tid] = bm[tid];
    lb[3 * 256 + tid] = bhpost[tid];
    lb[4 * 256 + tid] = br1[tid];
    lb[5 * 256 + tid] = Wr2[tid];
  }
  for (int i = tid; i < 8 * 512; i += 512) hB[i] = (__bf16)0.0f;  // h0 = 0
  const float br2v = br2[0];

  // bias/Wr2 accessor: element r of f32x4 <-> feature 16*mt + 4*lq + r
  #define BIAS(a, m) (*(const f32x4*)(lb + (a) * 256 + (m) * 16 + 4 * lq))
  const f32x4 w2a = *(const f32x4*)(Wr2 + mt0 * 16 + 4 * lq);
  const f32x4 w2b = *(const f32x4*)(Wr2 + (mt0 + 1) * 16 + 4 * lq);

  // ---- register-resident mesh weights: 32 frags = 128 VGPRs ----
  bf16x8 wm0[16], wm1[16];
  {
    const __bf16* mp = wsp + OFF_M + (size_t)(mt0 * 16) * 512 + lane * 8;
    #pragma unroll
    for (int kt = 0; kt < 16; ++kt) {
      wm0[kt] = *(const bf16x8*)(mp + kt * 512);
      wm1[kt] = *(const bf16x8*)(mp + (16 + kt) * 512);
    }
  }

  const __bf16* hp_p = wsp + OFF_HP + (size_t)(mt0 * 8) * 512 + lane * 8;
  const __bf16* r1_p = wsp + OFF_R1 + (size_t)(mt0 * 8) * 512 + lane * 8;
  const __bf16* cp_p = wsp + OFF_CP + (size_t)(mt0 * 2) * 512 + lane * 8;
  const __bf16* po_p = wsp + OFF_PO + (size_t)(mt0 * 8) * 512 + lane * 8;

  __syncthreads();

  // x for step t (re-prefetched each step during stage 2)
  const float* xbase = x + (size_t)(n0 + l15) * 64 + 8 * lq;
  f32x4 xr0 = *(const f32x4*)(xbase);
  f32x4 xr1 = *(const f32x4*)(xbase + 4);
  f32x4 xr2 = *(const f32x4*)(xbase + 32);
  f32x4 xr3 = *(const f32x4*)(xbase + 36);

  // hp fragments for step 0, depth-8 window
  bf16x8 hpb[8];
  #pragma unroll
  for (int p = 0; p < 8; ++p) hpb[p] = *(const bf16x8*)(hp_p + p * 512);

  for (int t = 0; t < TT; ++t) {
    // ---- deferred out store: outp was filled in stage 3 of step t-1 and
    // holds the row for out[t-2]. Reading here (after B3) keeps the whole
    // output head off the h-recurrence critical path.
    if (t >= 2 && tid < 16) {
      float s = br2v;
      #pragma unroll
      for (int w = 0; w < 8; ++w) s += outp[w * 16 + tid];
      out[(size_t)(t - 2) * NB + n0 + tid] = s;
    }

    bf16x8 Bx0, Bx1;
    #pragma unroll
    for (int j = 0; j < 4; ++j) {
      Bx0[j] = (__bf16)xr0[j]; Bx0[4 + j] = (__bf16)xr1[j];
      Bx1[j] = (__bf16)xr2[j]; Bx1[4 + j] = (__bf16)xr3[j];
    }

    // ---- stage 1: hp = h@Whp + bhp ; cp = x@Wcp + bcp ----
    bf16x8 cpb[4];
    #pragma unroll
    for (int p = 0; p < 4; ++p) cpb[p] = *(const bf16x8*)(cp_p + p * 512);
    bf16x8 Bh[8];
    #pragma unroll
    for (int kt = 0; kt < 8; ++kt)
      Bh[kt] = *(const bf16x8*)(hB + kt * 512 + lane * 8);

    f32x4 ah0 = BIAS(0, mt0), ah1 = BIAS(0, mt0 + 1);
    #pragma unroll
    for (int i = 0; i < 16; ++i) {       // frag i = (mt0 + (i>>3), kt = i&7)
      bf16x8 a = hpb[i & 7];
      if (i < 8) ah0 = MFMA(a, Bh[i & 7], ah0);
      else       ah1 = MFMA(a, Bh[i & 7], ah1);
      if (i + 8 < 16) hpb[i & 7] = *(const bf16x8*)(hp_p + (i + 8) * 512);
    }
    f32x4 ac0 = BIAS(1, mt0), ac1 = BIAS(1, mt0 + 1);
    ac0 = MFMA(cpb[0], Bx0, ac0); ac0 = MFMA(cpb[1], Bx1, ac0);
    ac1 = MFMA(cpb[2], Bx0, ac1); ac1 = MFMA(cpb[3], Bx1, ac1);

    pack2(mB,           wv, lane, ah0, ah1);
    pack2(mB + 8 * 512, wv, lane, ac0, ac1);
    barrier_lds();  // B1

    // ---- stage 2: u = cat@Wm + bm (wm resident, zero loads) ;
    //               r1 = h@Wr1 + br1 (reuses register Bh; loads hide under MFMAs)
    bf16x8 r1b[8];
    #pragma unroll
    for (int p = 0; p < 8; ++p) r1b[p] = *(const bf16x8*)(r1_p + p * 512);
    f32x4 am0 = BIAS(2, mt0), am1 = BIAS(2, mt0 + 1);
    f32x4 ar0 = BIAS(4, mt0), ar1 = BIAS(4, mt0 + 1);
    #pragma unroll
    for (int i = 0; i < 16; ++i) {
      bf16x8 Bm = *(const bf16x8*)(mB + i * 512 + lane * 8);
      am0 = MFMA(wm0[i], Bm, am0);
      am1 = MFMA(wm1[i], Bm, am1);
      bf16x8 a = r1b[i & 7];
      if (i < 8) ar0 = MFMA(a, Bh[i & 7], ar0);
      else       ar1 = MFMA(a, Bh[i & 7], ar1);
      if (i + 8 < 16) r1b[i & 7] = *(const bf16x8*)(r1_p + (i + 8) * 512);
    }
    // prefetch: first half of po frags + next step's x. With raw barriers
    // these now genuinely stay in flight across B2/B3 (no vmcnt drain).
    bf16x8 pob[8];
    #pragma unroll
    for (int p = 0; p < 8; ++p) pob[p] = *(const bf16x8*)(po_p + p * 512);
    {
      int tn = (t + 1 < TT) ? t + 1 : TT - 1;
      const float* xp = xbase + (size_t)tn * NB * 64;
      xr0 = *(const f32x4*)(xp);      xr1 = *(const f32x4*)(xp + 4);
      xr2 = *(const f32x4*)(xp + 32); xr3 = *(const f32x4*)(xp + 36);
    }
    pack2(uB, wv, lane, am0, am1);
    barrier_lds();  // B2

    // ---- stage 3: h = tanh(u @ Whpost + bhpost) ----
    bf16x8 Bu[8];
    #pragma unroll
    for (int kt = 0; kt < 8; ++kt)
      Bu[kt] = *(const bf16x8*)(uB + kt * 512 + lane * 8);
    // out-head reduction moved here: its VALU fills the uB ds_read latency
    // instead of sitting between the mesh MFMAs and B2. outp is consumed at
    // the top of step t+1 (WAR protected by B1/B2 of step t+1).
    {
      float p = 0.f;
      #pragma unroll
      for (int r = 0; r < 4; ++r)
        p += fmaxf(ar0[r], 0.f) * w2a[r] + fmaxf(ar1[r], 0.f) * w2b[r];
      p += __shfl_xor(p, 16, 64);
      p += __shfl_xor(p, 32, 64);
      if (lane < 16) outp[wv * 16 + lane] = p;
    }
    f32x4 ap0 = BIAS(3, mt0), ap1 = BIAS(3, mt0 + 1);
    #pragma unroll
    for (int i = 0; i < 16; ++i) {
      bf16x8 a = pob[i & 7];
      if (i < 8) ap0 = MFMA(a, Bu[i & 7], ap0);
      else       ap1 = MFMA(a, Bu[i & 7], ap1);
      if (i + 8 < 16) pob[i & 7] = *(const bf16x8*)(po_p + (i + 8) * 512);
    }
    pack2(hB, wv, lane, ap0, ap1);
    // prefetch next step's hp window (now flies across B3 uninterrupted)
    #pragma unroll
    for (int p = 0; p < 8; ++p) hpb[p] = *(const bf16x8*)(hp_p + p * 512);
    barrier_lds();  // B3
  }

  // ---- tail ----
  // flush out[TT-2] (outp written in stage 3 of t = TT-1)
  if (tid < 16) {
    float s = br2v;
    #pragma unroll
    for (int w = 0; w < 8; ++w) s += outp[w * 16 + tid];
    out[(size_t)(TT - 2) * NB + n0 + tid] = s;
  }
  barrier_lds();  // protect outp WAR before the final-r1 rewrite

  // regressor on final h -> out[TT-1]
  {
    bf16x8 Bh[8];
    #pragma unroll
    for (int kt = 0; kt < 8; ++kt)
      Bh[kt] = *(const bf16x8*)(hB + kt * 512 + lane * 8);
    f32x4 ar0 = BIAS(4, mt0), ar1 = BIAS(4, mt0 + 1);
    bf16x8 r1b[8];
    #pragma unroll
    for (int p = 0; p < 8; ++p) r1b[p] = *(const bf16x8*)(r1_p + p * 512);
    #pragma unroll
    for (int i = 0; i < 16; ++i) {
      bf16x8 a = r1b[i & 7];
      if (i < 8) ar0 = MFMA(a, Bh[i & 7], ar0);
      else       ar1 = MFMA(a, Bh[i & 7], ar1);
      if (i + 8 < 16) r1b[i & 7] = *(const bf16x8*)(r1_p + (i + 8) * 512);
    }
    float p = 0.f;
    #pragma unroll
    for (int r = 0; r < 4; ++r)
      p += fmaxf(ar0[r], 0.f) * w2a[r] + fmaxf(ar1[r], 0.f) * w2b[r];
    p += __shfl_xor(p, 16, 64);
    p += __shfl_xor(p, 32, 64);
    if (lane < 16) outp[wv * 16 + lane] = p;
    barrier_lds();
    if (tid < 16) {
      float s = br2v;
      #pragma unroll
      for (int w = 0; w < 8; ++w) s += outp[w * 16 + tid];
      out[(size_t)(TT - 1) * NB + n0 + tid] = s;
    }
  }
}

extern "C" void kernel_launch(void* const* d_in, const int* in_sizes, int n_in,
                              void* d_out, int out_size, void* d_ws, size_t ws_size,
                              hipStream_t stream) {
  const float* x      = (const float*)d_in[0];
  const float* Whp    = (const float*)d_in[1];
  const float* bhp    = (const float*)d_in[2];
  const float* Wcp    = (const float*)d_in[3];
  const float* bcp    = (const float*)d_in[4];
  const float* Wm     = (const float*)d_in[5];
  const float* bm     = (const float*)d_in[6];
  const float* Whpost = (const float*)d_in[7];
  const float* bhpost = (const float*)d_in[8];
  const float* Wr1    = (const float*)d_in[9];
  const float* br1    = (const float*)d_in[10];
  const float* Wr2    = (const float*)d_in[11];
  const float* br2    = (const float*)d_in[12];
  __bf16* wsp = (__bf16*)d_ws;
  float*  out = (float*)d_out;

  if (ws_size < (size_t)TOT * sizeof(__bf16)) return;

  pack_weights<<<(TOT + 255) / 256, 256, 0, stream>>>(Whp, Wm, Wcp, Whpost, Wr1, wsp);
  rnn_seq<<<64, 512, 0, stream>>>(x, wsp, bhp, bcp, bm, bhpost, br1, Wr2, br2, out);
}

// Round 2
// 5737.078 us; speedup vs baseline: 1.0712x; 1.0143x over previous
//
#include <hip/hip_runtime.h>
#include <hip/hip_bf16.h>

#define TT 512
#define NB 1024

typedef float f32x4 __attribute__((ext_vector_type(4)));
typedef __bf16 bf16x8 __attribute__((ext_vector_type(8)));

// ---- workspace layout (bf16 elems). All matrices stored as A-fragments for
// the TRANSPOSED GEMM  C^T[feature][batch] = W^T @ act^T :
//   frag(mt, kt, lane, j) at ((mt*KT + kt)*512 + lane*8 + j)
//   value = W[kappa][16*mt + (lane&15)]
// For weights consuming register-resident activations (Whp, Wm, Whpost, Wr1):
//   kappa = 32*kt + 16*(j>>2) + 4*(lane>>4) + (j&3)  [pi-permutation: B-frag ==
//   accumulator contents of the producing stage]. For Wcp (consumes x):
//   kappa = 32*kt + 8*(lane>>4) + j (natural).
#define OFF_HP 0
#define OFF_CP 65536
#define OFF_M  81920
#define OFF_PO 212992
#define OFF_R1 278528
#define TOT    344064

__global__ __launch_bounds__(256) void pack_weights(
    const float* __restrict__ Whp, const float* __restrict__ Wm,
    const float* __restrict__ Wcp, const float* __restrict__ Whpost,
    const float* __restrict__ Wr1, __bf16* __restrict__ wsp) {
  int id = blockIdx.x * 256 + threadIdx.x;
  if (id >= TOT) return;
  int j = id & 7, lane = (id >> 3) & 63;
  int lq = lane >> 4, l15 = lane & 15;
  int rel, KT; const float* W; bool perm = true;
  if (id < OFF_CP)      { rel = id;          KT = 8;  W = Whp; }
  else if (id < OFF_M)  { rel = id - OFF_CP; KT = 2;  W = Wcp; perm = false; }
  else if (id < OFF_PO) { rel = id - OFF_M;  KT = 16; W = Wm; }
  else if (id < OFF_R1) { rel = id - OFF_PO; KT = 8;  W = Whpost; }
  else                  { rel = id - OFF_R1; KT = 8;  W = Wr1; }
  int ktm = rel >> 9;
  int kt = ktm % KT, mt = ktm / KT;
  int phi = 16 * mt + l15;
  int kk;
  if (perm) {
    int kb = (kt >= 8) ? kt - 8 : kt;          // only mesh has kt>=8
    kk = 32 * kb + 16 * (j >> 2) + 4 * lq + (j & 3);
    if (kt >= 8) kk += 256;                    // cp half of the concat
  } else {
    kk = 32 * kt + 8 * lq + j;
  }
  wsp[id] = (__bf16)W[kk * 256 + phi];
}

__device__ __forceinline__ float tanh_fast(float x) {
  float t = __expf(2.0f * x);
  return 1.0f - __fdividef(2.0f, t + 1.0f);
}

#define MFMA(a, b, c) __builtin_amdgcn_mfma_f32_16x16x32_bf16((a), (b), (c), 0, 0, 0)

// tanh + pack this wave's two accumulators into ONE B-fragment (kt = wv).
// Pure in-lane: B[wv][j] = tanh(acc[j>>2][j&3]). Conflict-free ds_write_b128.
__device__ __forceinline__ void pack2(__bf16* region, int wv, int lane,
                                      const f32x4& a0, const f32x4& a1) {
  bf16x8 f;
  #pragma unroll
  for (int r = 0; r < 4; ++r) {
    f[r]     = (__bf16)tanh_fast(a0[r]);
    f[4 + r] = (__bf16)tanh_fast(a1[r]);
  }
  *(bf16x8*)(region + wv * 512 + lane * 8) = f;
}

// Raw barrier: make LDS writes visible (lgkmcnt only) WITHOUT draining vmcnt.
// __syncthreads() would emit s_waitcnt vmcnt(0) before s_barrier, forcing the
// cross-barrier global prefetches (x, hp/po weight frags) to complete at
// every barrier. This keeps them in flight; the compiler still inserts the
// correct vmcnt waits before each load's first use.
__device__ __forceinline__ void barrier_lds() {
  asm volatile("s_waitcnt lgkmcnt(0)" ::: "memory");
  __builtin_amdgcn_s_barrier();
  asm volatile("" ::: "memory");
}

__global__ __launch_bounds__(512)
__attribute__((amdgpu_waves_per_eu(2, 2)))   // force 256-VGPR budget: wm MUST stay resident
void rnn_seq(
    const float* __restrict__ x, const __bf16* __restrict__ wsp,
    const float* __restrict__ bhp, const float* __restrict__ bcp,
    const float* __restrict__ bm, const float* __restrict__ bhpost,
    const float* __restrict__ br1, const float* __restrict__ Wr2,
    const float* __restrict__ br2, float* __restrict__ out) {
  __shared__ __align__(16) __bf16 hB[8 * 512];       // h state as B-frags
  __shared__ __align__(16) __bf16 mB[16 * 512];      // [hpB | cpB] for mesh
  __shared__ __align__(16) __bf16 uB[8 * 512];       // mesh output
  __shared__ __align__(16) __bf16 r1L[112 * 512];    // Wr1 frags, kt 0..6 (112 KB)
  __shared__ float lb[5 * 256];                      // bhp,bcp,bm,bhpost,br1
  __shared__ float outp[128];

  const int tid  = threadIdx.x;
  const int wv   = tid >> 6;      // 0..7, owns m-tiles 2wv, 2wv+1
  const int lane = tid & 63;
  const int lq   = lane >> 4, l15 = lane & 15;
  const int n0   = blockIdx.x * 16;
  const int mt0  = 2 * wv;

  if (tid < 256) {
    lb[0 * 256 + tid] = bhp[tid];
    lb[1 * 256 + tid] = bcp[tid];
    lb[2 * 256 + tid] = bm[tid];
    lb[3 * 256 + tid] = bhpost[tid];
    lb[4 * 256 + tid] = br1[tid];
  }
  for (int i = tid; i < 8 * 512; i += 512) hB[i] = (__bf16)0.0f;  // h0 = 0

  // ---- one-time: cache Wr1 frags (kt 0..6 of every m-tile) in LDS.
  // LDS frag (mt,kt) at (mt*7+kt)*512 ; source frag (mt,kt) at (mt*8+kt)*512.
  for (int v = tid; v < 112 * 64; v += 512) {
    int frag = v >> 6, lp = v & 63;
    int mt = frag / 7, kt = frag - mt * 7;
    ((bf16x8*)r1L)[v] =
        *(const bf16x8*)(wsp + OFF_R1 + (size_t)(mt * 8 + kt) * 512 + lp * 8);
  }
  const float br2v = br2[0];

  // bias accessor: element r of f32x4 <-> feature 16*mt + 4*lq + r
  #define BIAS(a, m) (*(const f32x4*)(lb + (a) * 256 + (m) * 16 + 4 * lq))
  const f32x4 w2a = *(const f32x4*)(Wr2 + mt0 * 16 + 4 * lq);
  const f32x4 w2b = *(const f32x4*)(Wr2 + (mt0 + 1) * 16 + 4 * lq);

  // ---- register-resident mesh weights: 32 frags = 128 VGPRs ----
  bf16x8 wm0[16], wm1[16];
  {
    const __bf16* mp = wsp + OFF_M + (size_t)(mt0 * 16) * 512 + lane * 8;
    #pragma unroll
    for (int kt = 0; kt < 16; ++kt) {
      wm0[kt] = *(const bf16x8*)(mp + kt * 512);
      wm1[kt] = *(const bf16x8*)(mp + (16 + kt) * 512);
    }
  }

  const __bf16* hp_p = wsp + OFF_HP + (size_t)(mt0 * 8) * 512 + lane * 8;
  const __bf16* r1_p = wsp + OFF_R1 + (size_t)(mt0 * 8) * 512 + lane * 8;
  const __bf16* cp_p = wsp + OFF_CP + (size_t)(mt0 * 2) * 512 + lane * 8;
  const __bf16* po_p = wsp + OFF_PO + (size_t)(mt0 * 8) * 512 + lane * 8;
  const __bf16* r1Lp = r1L + (size_t)(mt0 * 7) * 512 + lane * 8;

  __syncthreads();

  // x for step t (re-prefetched each step during stage 2)
  const float* xbase = x + (size_t)(n0 + l15) * 64 + 8 * lq;
  f32x4 xr0 = *(const f32x4*)(xbase);
  f32x4 xr1 = *(const f32x4*)(xbase + 4);
  f32x4 xr2 = *(const f32x4*)(xbase + 32);
  f32x4 xr3 = *(const f32x4*)(xbase + 36);

  // hp fragments for step 0, depth-8 window
  bf16x8 hpb[8];
  #pragma unroll
  for (int p = 0; p < 8; ++p) hpb[p] = *(const bf16x8*)(hp_p + p * 512);

  for (int t = 0; t < TT; ++t) {
    // ---- deferred out store: outp was filled in stage 3 of step t-1 and
    // holds the row for out[t-2]. Reading here (after B3) keeps the whole
    // output head off the h-recurrence critical path.
    if (t >= 2 && tid < 16) {
      float s = br2v;
      #pragma unroll
      for (int w = 0; w < 8; ++w) s += outp[w * 16 + tid];
      out[(size_t)(t - 2) * NB + n0 + tid] = s;
    }

    bf16x8 Bx0, Bx1;
    #pragma unroll
    for (int j = 0; j < 4; ++j) {
      Bx0[j] = (__bf16)xr0[j]; Bx0[4 + j] = (__bf16)xr1[j];
      Bx1[j] = (__bf16)xr2[j]; Bx1[4 + j] = (__bf16)xr3[j];
    }

    // ---- stage 1: hp = h@Whp + bhp ; cp = x@Wcp + bcp ----
    // also issue the streamed r1 kt=7 frags now (consumed late in stage 2:
    // ~600 cy of lead instead of the old zero-lead r1b window).
    bf16x8 cpb[4];
    #pragma unroll
    for (int p = 0; p < 4; ++p) cpb[p] = *(const bf16x8*)(cp_p + p * 512);
    bf16x8 r1k7a = *(const bf16x8*)(r1_p + 7 * 512);
    bf16x8 r1k7b = *(const bf16x8*)(r1_p + 15 * 512);
    bf16x8 Bh[8];
    #pragma unroll
    for (int kt = 0; kt < 8; ++kt)
      Bh[kt] = *(const bf16x8*)(hB + kt * 512 + lane * 8);

    f32x4 ah0 = BIAS(0, mt0), ah1 = BIAS(0, mt0 + 1);
    #pragma unroll
    for (int i = 0; i < 16; ++i) {       // frag i = (mt0 + (i>>3), kt = i&7)
      bf16x8 a = hpb[i & 7];
      if (i < 8) ah0 = MFMA(a, Bh[i & 7], ah0);
      else       ah1 = MFMA(a, Bh[i & 7], ah1);
      if (i + 8 < 16) hpb[i & 7] = *(const bf16x8*)(hp_p + (i + 8) * 512);
    }
    f32x4 ac0 = BIAS(1, mt0), ac1 = BIAS(1, mt0 + 1);
    ac0 = MFMA(cpb[0], Bx0, ac0); ac0 = MFMA(cpb[1], Bx1, ac0);
    ac1 = MFMA(cpb[2], Bx0, ac1); ac1 = MFMA(cpb[3], Bx1, ac1);

    pack2(mB,           wv, lane, ah0, ah1);
    pack2(mB + 8 * 512, wv, lane, ac0, ac1);
    barrier_lds();  // B1

    // ---- stage 2: u = cat@Wm + bm (wm resident, zero loads) ;
    //               r1 = h@Wr1 + br1 (Wr1 kt0..6 from LDS, kt7 prefetched)
    f32x4 am0 = BIAS(2, mt0), am1 = BIAS(2, mt0 + 1);
    f32x4 ar0 = BIAS(4, mt0), ar1 = BIAS(4, mt0 + 1);
    #pragma unroll
    for (int i = 0; i < 16; ++i) {
      bf16x8 Bm = *(const bf16x8*)(mB + i * 512 + lane * 8);
      am0 = MFMA(wm0[i], Bm, am0);
      am1 = MFMA(wm1[i], Bm, am1);
      int k = i & 7;
      bf16x8 a;
      if (k < 7) a = *(const bf16x8*)(r1Lp + ((i >> 3) * 7 + k) * 512);
      else       a = (i < 8) ? r1k7a : r1k7b;
      if (i < 8) ar0 = MFMA(a, Bh[k], ar0);
      else       ar1 = MFMA(a, Bh[k], ar1);
    }
    // prefetch: first half of po frags + next step's x. With raw barriers
    // these genuinely stay in flight across B2/B3 (no vmcnt drain).
    bf16x8 pob[8];
    #pragma unroll
    for (int p = 0; p < 8; ++p) pob[p] = *(const bf16x8*)(po_p + p * 512);
    {
      int tn = (t + 1 < TT) ? t + 1 : TT - 1;
      const float* xp = xbase + (size_t)tn * NB * 64;
      xr0 = *(const f32x4*)(xp);      xr1 = *(const f32x4*)(xp + 4);
      xr2 = *(const f32x4*)(xp + 32); xr3 = *(const f32x4*)(xp + 36);
    }
    pack2(uB, wv, lane, am0, am1);
    barrier_lds();  // B2

    // ---- stage 3: h = tanh(u @ Whpost + bhpost) ----
    // prefetch next step's hp window FIRST: lead grows from ~250cy (old
    // placement at stage-3 end) to ~600cy (whole stage 3 + barrier).
    #pragma unroll
    for (int p = 0; p < 8; ++p) hpb[p] = *(const bf16x8*)(hp_p + p * 512);
    bf16x8 Bu[8];
    #pragma unroll
    for (int kt = 0; kt < 8; ++kt)
      Bu[kt] = *(const bf16x8*)(uB + kt * 512 + lane * 8);
    // out-head reduction: its VALU fills the uB ds_read latency. outp is
    // consumed at the top of step t+1 (WAR protected by B1/B2 of step t+1).
    {
      float p = 0.f;
      #pragma unroll
      for (int r = 0; r < 4; ++r)
        p += fmaxf(ar0[r], 0.f) * w2a[r] + fmaxf(ar1[r], 0.f) * w2b[r];
      p += __shfl_xor(p, 16, 64);
      p += __shfl_xor(p, 32, 64);
      if (lane < 16) outp[wv * 16 + lane] = p;
    }
    f32x4 ap0 = BIAS(3, mt0), ap1 = BIAS(3, mt0 + 1);
    #pragma unroll
    for (int i = 0; i < 16; ++i) {
      bf16x8 a = pob[i & 7];
      if (i < 8) ap0 = MFMA(a, Bu[i & 7], ap0);
      else       ap1 = MFMA(a, Bu[i & 7], ap1);
      if (i + 8 < 16) pob[i & 7] = *(const bf16x8*)(po_p + (i + 8) * 512);
    }
    pack2(hB, wv, lane, ap0, ap1);
    barrier_lds();  // B3
  }

  // ---- tail ----
  // flush out[TT-2] (outp written in stage 3 of t = TT-1)
  if (tid < 16) {
    float s = br2v;
    #pragma unroll
    for (int w = 0; w < 8; ++w) s += outp[w * 16 + tid];
    out[(size_t)(TT - 2) * NB + n0 + tid] = s;
  }
  barrier_lds();  // protect outp WAR before the final-r1 rewrite

  // regressor on final h -> out[TT-1]
  {
    bf16x8 Bh[8];
    #pragma unroll
    for (int kt = 0; kt < 8; ++kt)
      Bh[kt] = *(const bf16x8*)(hB + kt * 512 + lane * 8);
    f32x4 ar0 = BIAS(4, mt0), ar1 = BIAS(4, mt0 + 1);
    bf16x8 r1b[8];
    #pragma unroll
    for (int p = 0; p < 8; ++p) r1b[p] = *(const bf16x8*)(r1_p + p * 512);
    #pragma unroll
    for (int i = 0; i < 16; ++i) {
      bf16x8 a = r1b[i & 7];
      if (i < 8) ar0 = MFMA(a, Bh[i & 7], ar0);
      else       ar1 = MFMA(a, Bh[i & 7], ar1);
      if (i + 8 < 16) r1b[i & 7] = *(const bf16x8*)(r1_p + (i + 8) * 512);
    }
    float p = 0.f;
    #pragma unroll
    for (int r = 0; r < 4; ++r)
      p += fmaxf(ar0[r], 0.f) * w2a[r] + fmaxf(ar1[r], 0.f) * w2b[r];
    p += __shfl_xor(p, 16, 64);
    p += __shfl_xor(p, 32, 64);
    if (lane < 16) outp[wv * 16 + lane] = p;
    barrier_lds();
    if (tid < 16) {
      float s = br2v;
      #pragma unroll
      for (int w = 0; w < 8; ++w) s += outp[w * 16 + tid];
      out[(size_t)(TT - 1) * NB + n0 + tid] = s;
    }
  }
}

extern "C" void kernel_launch(void* const* d_in, const int* in_sizes, int n_in,
                              void* d_out, int out_size, void* d_ws, size_t ws_size,
                              hipStream_t stream) {
  const float* x      = (const float*)d_in[0];
  const float* Whp    = (const float*)d_in[1];
  const float* bhp    = (const float*)d_in[2];
  const float* Wcp    = (const float*)d_in[3];
  const float* bcp    = (const float*)d_in[4];
  const float* Wm     = (const float*)d_in[5];
  const float* bm     = (const float*)d_in[6];
  const float* Whpost = (const float*)d_in[7];
  const float* bhpost = (const float*)d_in[8];
  const float* Wr1    = (const float*)d_in[9];
  const float* br1    = (const float*)d_in[10];
  const float* Wr2    = (const float*)d_in[11];
  const float* br2    = (const float*)d_in[12];
  __bf16* wsp = (__bf16*)d_ws;
  float*  out = (float*)d_out;

  if (ws_size < (size_t)TOT * sizeof(__bf16)) return;

  pack_weights<<<(TOT + 255) / 256, 256, 0, stream>>>(Whp, Wm, Wcp, Whpost, Wr1, wsp);
  rnn_seq<<<64, 512, 0, stream>>>(x, wsp, bhp, bcp, bm, bhpost, br1, Wr2, br2, out);
}

// Round 3
// 5720.093 us; speedup vs baseline: 1.0744x; 1.0030x over previous
//
#include <hip/hip_runtime.h>
#include <hip/hip_bf16.h>

#define TT 512
#define NB 1024

typedef float f32x4 __attribute__((ext_vector_type(4)));
typedef __bf16 bf16x8 __attribute__((ext_vector_type(8)));

// ---- workspace layout (bf16 elems). All matrices stored as A-fragments for
// the TRANSPOSED GEMM  C^T[feature][batch] = W^T @ act^T :
//   frag(mt, kt, lane, j) at ((mt*KT + kt)*512 + lane*8 + j)
//   value = W[kappa][16*mt + (lane&15)]
// For weights consuming register-resident activations (Whp, Wm, Whpost, Wr1):
//   kappa = 32*kt + 16*(j>>2) + 4*(lane>>4) + (j&3)  [pi-permutation: B-frag ==
//   accumulator contents of the producing stage]. For Wcp (consumes x):
//   kappa = 32*kt + 8*(lane>>4) + j (natural).
#define OFF_HP 0
#define OFF_CP 65536
#define OFF_M  81920
#define OFF_PO 212992
#define OFF_R1 278528
#define TOT    344064

// G workspace: G[t][nb][thread][8] f32 = mesh cp-half + bm, precomputed.
// offset 1 MB into d_ws; 512*64*512*8*4 = 536,870,912 bytes.
#define G_OFF_BYTES (1u << 20)
#define G_STEP_FLOATS ((size_t)64 * 512 * 8)

__global__ __launch_bounds__(256) void pack_weights(
    const float* __restrict__ Whp, const float* __restrict__ Wm,
    const float* __restrict__ Wcp, const float* __restrict__ Whpost,
    const float* __restrict__ Wr1, __bf16* __restrict__ wsp) {
  int id = blockIdx.x * 256 + threadIdx.x;
  if (id >= TOT) return;
  int j = id & 7, lane = (id >> 3) & 63;
  int lq = lane >> 4, l15 = lane & 15;
  int rel, KT; const float* W; bool perm = true;
  if (id < OFF_CP)      { rel = id;          KT = 8;  W = Whp; }
  else if (id < OFF_M)  { rel = id - OFF_CP; KT = 2;  W = Wcp; perm = false; }
  else if (id < OFF_PO) { rel = id - OFF_M;  KT = 16; W = Wm; }
  else if (id < OFF_R1) { rel = id - OFF_PO; KT = 8;  W = Whpost; }
  else                  { rel = id - OFF_R1; KT = 8;  W = Wr1; }
  int ktm = rel >> 9;
  int kt = ktm % KT, mt = ktm / KT;
  int phi = 16 * mt + l15;
  int kk;
  if (perm) {
    int kb = (kt >= 8) ? kt - 8 : kt;          // only mesh has kt>=8
    kk = 32 * kb + 16 * (j >> 2) + 4 * lq + (j & 3);
    if (kt >= 8) kk += 256;                    // cp half of the concat
  } else {
    kk = 32 * kt + 8 * lq + j;
  }
  wsp[id] = (__bf16)W[kk * 256 + phi];
}

__device__ __forceinline__ float tanh_fast(float x) {
  float t = __expf(2.0f * x);
  return 1.0f - __fdividef(2.0f, t + 1.0f);
}

#define MFMA(a, b, c) __builtin_amdgcn_mfma_f32_16x16x32_bf16((a), (b), (c), 0, 0, 0)

// tanh + pack this wave's two accumulators into ONE B-fragment (kt = wv).
// Pure in-lane: B[wv][j] = tanh(acc[j>>2][j&3]). Conflict-free ds_write_b128.
__device__ __forceinline__ void pack2(__bf16* region, int wv, int lane,
                                      const f32x4& a0, const f32x4& a1) {
  bf16x8 f;
  #pragma unroll
  for (int r = 0; r < 4; ++r) {
    f[r]     = (__bf16)tanh_fast(a0[r]);
    f[4 + r] = (__bf16)tanh_fast(a1[r]);
  }
  *(bf16x8*)(region + wv * 512 + lane * 8) = f;
}

// Raw barrier: make LDS writes visible (lgkmcnt only) WITHOUT draining vmcnt.
__device__ __forceinline__ void barrier_lds() {
  asm volatile("s_waitcnt lgkmcnt(0)" ::: "memory");
  __builtin_amdgcn_s_barrier();
  asm volatile("" ::: "memory");
}

// ---------------------------------------------------------------------------
// gprep: fully parallel precompute of G[t] = tanh(x[t]@Wcp + bcp)@Wm_c + bm.
// One wave per 16 batch columns; no LDS, no barriers. Arithmetic matches the
// in-loop cp path exactly (same bf16 packing, same MFMA chains); only the f32
// add-order of the mesh accumulation changes (bm+cp-half first, hp-half later).
// ---------------------------------------------------------------------------
__global__ __launch_bounds__(64) void gprep(
    const float* __restrict__ x, const __bf16* __restrict__ wsp,
    const float* __restrict__ bcp, const float* __restrict__ bm,
    float* __restrict__ g) {
  const int b = blockIdx.x;                 // b = t*64 + nb
  const int t = b >> 6, nb = b & 63;
  const int lane = threadIdx.x;
  const int lq = lane >> 4, l15 = lane & 15;

  const float* xb = x + ((size_t)t * NB + nb * 16 + l15) * 64 + 8 * lq;
  f32x4 xr0 = *(const f32x4*)(xb);
  f32x4 xr1 = *(const f32x4*)(xb + 4);
  f32x4 xr2 = *(const f32x4*)(xb + 32);
  f32x4 xr3 = *(const f32x4*)(xb + 36);
  bf16x8 Bx0, Bx1;
  #pragma unroll
  for (int j = 0; j < 4; ++j) {
    Bx0[j] = (__bf16)xr0[j]; Bx0[4 + j] = (__bf16)xr1[j];
    Bx1[j] = (__bf16)xr2[j]; Bx1[4 + j] = (__bf16)xr3[j];
  }

  // cp for all 16 m-tiles (pairs p -> mt 2p,2p+1), packed in-lane to B-frags
  bf16x8 Bc[8];
  #pragma unroll
  for (int p = 0; p < 8; ++p) {
    const __bf16* cpf = wsp + OFF_CP + (size_t)(4 * p) * 512 + lane * 8;
    bf16x8 c0 = *(const bf16x8*)(cpf);
    bf16x8 c1 = *(const bf16x8*)(cpf + 512);
    bf16x8 c2 = *(const bf16x8*)(cpf + 1024);
    bf16x8 c3 = *(const bf16x8*)(cpf + 1536);
    f32x4 a0 = *(const f32x4*)(bcp + p * 32 + 4 * lq);        // mt = 2p
    f32x4 a1 = *(const f32x4*)(bcp + p * 32 + 16 + 4 * lq);   // mt = 2p+1
    a0 = MFMA(c0, Bx0, a0); a0 = MFMA(c1, Bx1, a0);
    a1 = MFMA(c2, Bx0, a1); a1 = MFMA(c3, Bx1, a1);
    bf16x8 f;
    #pragma unroll
    for (int r = 0; r < 4; ++r) {
      f[r]     = (__bf16)tanh_fast(a0[r]);
      f[4 + r] = (__bf16)tanh_fast(a1[r]);
    }
    Bc[p] = f;
  }

  // mesh cp-half: G(mt) = bm + sum_{kb} Wm[mt][8+kb] @ Bc[kb]
  float* gb = g + ((size_t)b * 512 + lane) * 8;
  #pragma unroll
  for (int p = 0; p < 8; ++p) {
    f32x4 a0 = *(const f32x4*)(bm + p * 32 + 4 * lq);
    f32x4 a1 = *(const f32x4*)(bm + p * 32 + 16 + 4 * lq);
    const __bf16* m0 = wsp + OFF_M + (size_t)((2 * p) * 16 + 8) * 512 + lane * 8;
    const __bf16* m1 = wsp + OFF_M + (size_t)((2 * p + 1) * 16 + 8) * 512 + lane * 8;
    #pragma unroll
    for (int kb = 0; kb < 8; ++kb) {
      a0 = MFMA(*(const bf16x8*)(m0 + kb * 512), Bc[kb], a0);
      a1 = MFMA(*(const bf16x8*)(m1 + kb * 512), Bc[kb], a1);
    }
    *(f32x4*)(gb + p * 512 + 0) = a0;
    *(f32x4*)(gb + p * 512 + 4) = a1;
  }
}

// ---------------------------------------------------------------------------
// Lean sequential kernel: per step only hp (16 MFMA) -> mesh_h (16, resident)
// + G[t] -> po (16), with the overlapped out-head. No x / Bx / cp in the loop.
// ---------------------------------------------------------------------------
__global__ __launch_bounds__(512)
__attribute__((amdgpu_waves_per_eu(2, 2)))
void rnn_seq_lean(
    const __bf16* __restrict__ wsp, const float* __restrict__ gws,
    const float* __restrict__ bhp, const float* __restrict__ bcp,
    const float* __restrict__ bm, const float* __restrict__ bhpost,
    const float* __restrict__ br1, const float* __restrict__ Wr2,
    const float* __restrict__ br2, float* __restrict__ out) {
  __shared__ __align__(16) __bf16 hB[8 * 512];       // h state as B-frags
  __shared__ __align__(16) __bf16 mB[8 * 512];       // hp B-frags for mesh
  __shared__ __align__(16) __bf16 uB[8 * 512];       // mesh output
  __shared__ __align__(16) __bf16 r1L[112 * 512];    // Wr1 frags, kt 0..6
  __shared__ float lb[5 * 256];
  __shared__ float outp[128];

  const int tid  = threadIdx.x;
  const int wv   = tid >> 6;
  const int lane = tid & 63;
  const int lq   = lane >> 4;
  const int n0   = blockIdx.x * 16;
  const int mt0  = 2 * wv;

  if (tid < 256) {
    lb[0 * 256 + tid] = bhp[tid];
    lb[1 * 256 + tid] = bcp[tid];
    lb[2 * 256 + tid] = bm[tid];
    lb[3 * 256 + tid] = bhpost[tid];
    lb[4 * 256 + tid] = br1[tid];
  }
  for (int i = tid; i < 8 * 512; i += 512) hB[i] = (__bf16)0.0f;

  for (int v = tid; v < 112 * 64; v += 512) {
    int frag = v >> 6, lp = v & 63;
    int mt = frag / 7, kt = frag - mt * 7;
    ((bf16x8*)r1L)[v] =
        *(const bf16x8*)(wsp + OFF_R1 + (size_t)(mt * 8 + kt) * 512 + lp * 8);
  }
  const float br2v = br2[0];

  #define BIAS(a, m) (*(const f32x4*)(lb + (a) * 256 + (m) * 16 + 4 * lq))
  const f32x4 w2a = *(const f32x4*)(Wr2 + mt0 * 16 + 4 * lq);
  const f32x4 w2b = *(const f32x4*)(Wr2 + (mt0 + 1) * 16 + 4 * lq);

  // register-resident mesh hp-half weights: 16 frags = 64 VGPRs
  bf16x8 wm0h[8], wm1h[8];
  {
    const __bf16* mp = wsp + OFF_M + (size_t)(mt0 * 16) * 512 + lane * 8;
    #pragma unroll
    for (int kt = 0; kt < 8; ++kt) {
      wm0h[kt] = *(const bf16x8*)(mp + kt * 512);
      wm1h[kt] = *(const bf16x8*)(mp + (16 + kt) * 512);
    }
  }

  const __bf16* hp_p = wsp + OFF_HP + (size_t)(mt0 * 8) * 512 + lane * 8;
  const __bf16* r1_p = wsp + OFF_R1 + (size_t)(mt0 * 8) * 512 + lane * 8;
  const __bf16* po_p = wsp + OFF_PO + (size_t)(mt0 * 8) * 512 + lane * 8;
  const __bf16* r1Lp = r1L + (size_t)(mt0 * 7) * 512 + lane * 8;
  const float*  gp   = gws + ((size_t)blockIdx.x * 512 + tid) * 8;

  __syncthreads();

  // G for step 0
  f32x4 g0c = *(const f32x4*)(gp);
  f32x4 g1c = *(const f32x4*)(gp + 4);
  f32x4 g0n, g1n;

  bf16x8 hpb[8];
  #pragma unroll
  for (int p = 0; p < 8; ++p) hpb[p] = *(const bf16x8*)(hp_p + p * 512);

  for (int t = 0; t < TT; ++t) {
    if (t >= 2 && tid < 16) {
      float s = br2v;
      #pragma unroll
      for (int w = 0; w < 8; ++w) s += outp[w * 16 + tid];
      out[(size_t)(t - 2) * NB + n0 + tid] = s;
    }

    // ---- stage 1: hp = h@Whp + bhp ----
    bf16x8 r1k7a = *(const bf16x8*)(r1_p + 7 * 512);
    bf16x8 r1k7b = *(const bf16x8*)(r1_p + 15 * 512);
    bf16x8 Bh[8];
    #pragma unroll
    for (int kt = 0; kt < 8; ++kt)
      Bh[kt] = *(const bf16x8*)(hB + kt * 512 + lane * 8);

    f32x4 ah0 = BIAS(0, mt0), ah1 = BIAS(0, mt0 + 1);
    #pragma unroll
    for (int i = 0; i < 16; ++i) {
      bf16x8 a = hpb[i & 7];
      if (i < 8) ah0 = MFMA(a, Bh[i & 7], ah0);
      else       ah1 = MFMA(a, Bh[i & 7], ah1);
      if (i + 8 < 16) hpb[i & 7] = *(const bf16x8*)(hp_p + (i + 8) * 512);
    }
    pack2(mB, wv, lane, ah0, ah1);
    barrier_lds();  // B1

    // ---- stage 2: u = hp-half mesh + G[t] ; r1 = h@Wr1 + br1 ----
    f32x4 am0 = g0c, am1 = g1c;     // G already contains bm + cp-half
    f32x4 ar0 = BIAS(4, mt0), ar1 = BIAS(4, mt0 + 1);
    #pragma unroll
    for (int i = 0; i < 16; ++i) {
      if (i < 8) {
        bf16x8 Bm = *(const bf16x8*)(mB + i * 512 + lane * 8);
        am0 = MFMA(wm0h[i], Bm, am0);
        am1 = MFMA(wm1h[i], Bm, am1);
      }
      int k = i & 7;
      bf16x8 a;
      if (k < 7) a = *(const bf16x8*)(r1Lp + ((i >> 3) * 7 + k) * 512);
      else       a = (i < 8) ? r1k7a : r1k7b;
      if (i < 8) ar0 = MFMA(a, Bh[k], ar0);
      else       ar1 = MFMA(a, Bh[k], ar1);
    }
    // prefetch: po first half + next step's G (in flight across B2/B3)
    bf16x8 pob[8];
    #pragma unroll
    for (int p = 0; p < 8; ++p) pob[p] = *(const bf16x8*)(po_p + p * 512);
    {
      int tn = (t + 1 < TT) ? t + 1 : TT - 1;
      const float* gpn = gp + (size_t)tn * G_STEP_FLOATS;
      g0n = *(const f32x4*)(gpn);
      g1n = *(const f32x4*)(gpn + 4);
    }
    pack2(uB, wv, lane, am0, am1);
    barrier_lds();  // B2

    // ---- stage 3: h = tanh(u @ Whpost + bhpost) ----
    #pragma unroll
    for (int p = 0; p < 8; ++p) hpb[p] = *(const bf16x8*)(hp_p + p * 512);
    bf16x8 Bu[8];
    #pragma unroll
    for (int kt = 0; kt < 8; ++kt)
      Bu[kt] = *(const bf16x8*)(uB + kt * 512 + lane * 8);
    {
      float p = 0.f;
      #pragma unroll
      for (int r = 0; r < 4; ++r)
        p += fmaxf(ar0[r], 0.f) * w2a[r] + fmaxf(ar1[r], 0.f) * w2b[r];
      p += __shfl_xor(p, 16, 64);
      p += __shfl_xor(p, 32, 64);
      if (lane < 16) outp[wv * 16 + lane] = p;
    }
    f32x4 ap0 = BIAS(3, mt0), ap1 = BIAS(3, mt0 + 1);
    #pragma unroll
    for (int i = 0; i < 16; ++i) {
      bf16x8 a = pob[i & 7];
      if (i < 8) ap0 = MFMA(a, Bu[i & 7], ap0);
      else       ap1 = MFMA(a, Bu[i & 7], ap1);
      if (i + 8 < 16) pob[i & 7] = *(const bf16x8*)(po_p + (i + 8) * 512);
    }
    pack2(hB, wv, lane, ap0, ap1);
    barrier_lds();  // B3
    g0c = g0n; g1c = g1n;
  }

  // ---- tail ----
  if (tid < 16) {
    float s = br2v;
    #pragma unroll
    for (int w = 0; w < 8; ++w) s += outp[w * 16 + tid];
    out[(size_t)(TT - 2) * NB + n0 + tid] = s;
  }
  barrier_lds();

  {
    bf16x8 Bh[8];
    #pragma unroll
    for (int kt = 0; kt < 8; ++kt)
      Bh[kt] = *(const bf16x8*)(hB + kt * 512 + lane * 8);
    f32x4 ar0 = BIAS(4, mt0), ar1 = BIAS(4, mt0 + 1);
    bf16x8 r1b[8];
    #pragma unroll
    for (int p = 0; p < 8; ++p) r1b[p] = *(const bf16x8*)(r1_p + p * 512);
    #pragma unroll
    for (int i = 0; i < 16; ++i) {
      bf16x8 a = r1b[i & 7];
      if (i < 8) ar0 = MFMA(a, Bh[i & 7], ar0);
      else       ar1 = MFMA(a, Bh[i & 7], ar1);
      if (i + 8 < 16) r1b[i & 7] = *(const bf16x8*)(r1_p + (i + 8) * 512);
    }
    float p = 0.f;
    #pragma unroll
    for (int r = 0; r < 4; ++r)
      p += fmaxf(ar0[r], 0.f) * w2a[r] + fmaxf(ar1[r], 0.f) * w2b[r];
    p += __shfl_xor(p, 16, 64);
    p += __shfl_xor(p, 32, 64);
    if (lane < 16) outp[wv * 16 + lane] = p;
    barrier_lds();
    if (tid < 16) {
      float s = br2v;
      #pragma unroll
      for (int w = 0; w < 8; ++w) s += outp[w * 16 + tid];
      out[(size_t)(TT - 1) * NB + n0 + tid] = s;
    }
  }
}

// ---------------------------------------------------------------------------
// Fallback: R2 kernel verbatim (used when workspace is too small for G).
// ---------------------------------------------------------------------------
__global__ __launch_bounds__(512)
__attribute__((amdgpu_waves_per_eu(2, 2)))
void rnn_seq(
    const float* __restrict__ x, const __bf16* __restrict__ wsp,
    const float* __restrict__ bhp, const float* __restrict__ bcp,
    const float* __restrict__ bm, const float* __restrict__ bhpost,
    const float* __restrict__ br1, const float* __restrict__ Wr2,
    const float* __restrict__ br2, float* __restrict__ out) {
  __shared__ __align__(16) __bf16 hB[8 * 512];
  __shared__ __align__(16) __bf16 mB[16 * 512];
  __shared__ __align__(16) __bf16 uB[8 * 512];
  __shared__ __align__(16) __bf16 r1L[112 * 512];
  __shared__ float lb[5 * 256];
  __shared__ float outp[128];

  const int tid  = threadIdx.x;
  const int wv   = tid >> 6;
  const int lane = tid & 63;
  const int lq   = lane >> 4, l15 = lane & 15;
  const int n0   = blockIdx.x * 16;
  const int mt0  = 2 * wv;

  if (tid < 256) {
    lb[0 * 256 + tid] = bhp[tid];
    lb[1 * 256 + tid] = bcp[tid];
    lb[2 * 256 + tid] = bm[tid];
    lb[3 * 256 + tid] = bhpost[tid];
    lb[4 * 256 + tid] = br1[tid];
  }
  for (int i = tid; i < 8 * 512; i += 512) hB[i] = (__bf16)0.0f;

  for (int v = tid; v < 112 * 64; v += 512) {
    int frag = v >> 6, lp = v & 63;
    int mt = frag / 7, kt = frag - mt * 7;
    ((bf16x8*)r1L)[v] =
        *(const bf16x8*)(wsp + OFF_R1 + (size_t)(mt * 8 + kt) * 512 + lp * 8);
  }
  const float br2v = br2[0];

  const f32x4 w2a = *(const f32x4*)(Wr2 + mt0 * 16 + 4 * lq);
  const f32x4 w2b = *(const f32x4*)(Wr2 + (mt0 + 1) * 16 + 4 * lq);

  bf16x8 wm0[16], wm1[16];
  {
    const __bf16* mp = wsp + OFF_M + (size_t)(mt0 * 16) * 512 + lane * 8;
    #pragma unroll
    for (int kt = 0; kt < 16; ++kt) {
      wm0[kt] = *(const bf16x8*)(mp + kt * 512);
      wm1[kt] = *(const bf16x8*)(mp + (16 + kt) * 512);
    }
  }

  const __bf16* hp_p = wsp + OFF_HP + (size_t)(mt0 * 8) * 512 + lane * 8;
  const __bf16* r1_p = wsp + OFF_R1 + (size_t)(mt0 * 8) * 512 + lane * 8;
  const __bf16* cp_p = wsp + OFF_CP + (size_t)(mt0 * 2) * 512 + lane * 8;
  const __bf16* po_p = wsp + OFF_PO + (size_t)(mt0 * 8) * 512 + lane * 8;
  const __bf16* r1Lp = r1L + (size_t)(mt0 * 7) * 512 + lane * 8;

  __syncthreads();

  const float* xbase = x + (size_t)(n0 + l15) * 64 + 8 * lq;
  f32x4 xr0 = *(const f32x4*)(xbase);
  f32x4 xr1 = *(const f32x4*)(xbase + 4);
  f32x4 xr2 = *(const f32x4*)(xbase + 32);
  f32x4 xr3 = *(const f32x4*)(xbase + 36);

  bf16x8 hpb[8];
  #pragma unroll
  for (int p = 0; p < 8; ++p) hpb[p] = *(const bf16x8*)(hp_p + p * 512);

  for (int t = 0; t < TT; ++t) {
    if (t >= 2 && tid < 16) {
      float s = br2v;
      #pragma unroll
      for (int w = 0; w < 8; ++w) s += outp[w * 16 + tid];
      out[(size_t)(t - 2) * NB + n0 + tid] = s;
    }

    bf16x8 Bx0, Bx1;
    #pragma unroll
    for (int j = 0; j < 4; ++j) {
      Bx0[j] = (__bf16)xr0[j]; Bx0[4 + j] = (__bf16)xr1[j];
      Bx1[j] = (__bf16)xr2[j]; Bx1[4 + j] = (__bf16)xr3[j];
    }

    bf16x8 cpb[4];
    #pragma unroll
    for (int p = 0; p < 4; ++p) cpb[p] = *(const bf16x8*)(cp_p + p * 512);
    bf16x8 r1k7a = *(const bf16x8*)(r1_p + 7 * 512);
    bf16x8 r1k7b = *(const bf16x8*)(r1_p + 15 * 512);
    bf16x8 Bh[8];
    #pragma unroll
    for (int kt = 0; kt < 8; ++kt)
      Bh[kt] = *(const bf16x8*)(hB + kt * 512 + lane * 8);

    f32x4 ah0 = BIAS(0, mt0), ah1 = BIAS(0, mt0 + 1);
    #pragma unroll
    for (int i = 0; i < 16; ++i) {
      bf16x8 a = hpb[i & 7];
      if (i < 8) ah0 = MFMA(a, Bh[i & 7], ah0);
      else       ah1 = MFMA(a, Bh[i & 7], ah1);
      if (i + 8 < 16) hpb[i & 7] = *(const bf16x8*)(hp_p + (i + 8) * 512);
    }
    f32x4 ac0 = BIAS(1, mt0), ac1 = BIAS(1, mt0 + 1);
    ac0 = MFMA(cpb[0], Bx0, ac0); ac0 = MFMA(cpb[1], Bx1, ac0);
    ac1 = MFMA(cpb[2], Bx0, ac1); ac1 = MFMA(cpb[3], Bx1, ac1);

    pack2(mB,           wv, lane, ah0, ah1);
    pack2(mB + 8 * 512, wv, lane, ac0, ac1);
    barrier_lds();  // B1

    f32x4 am0 = BIAS(2, mt0), am1 = BIAS(2, mt0 + 1);
    f32x4 ar0 = BIAS(4, mt0), ar1 = BIAS(4, mt0 + 1);
    #pragma unroll
    for (int i = 0; i < 16; ++i) {
      bf16x8 Bm = *(const bf16x8*)(mB + i * 512 + lane * 8);
      am0 = MFMA(wm0[i], Bm, am0);
      am1 = MFMA(wm1[i], Bm, am1);
      int k = i & 7;
      bf16x8 a;
      if (k < 7) a = *(const bf16x8*)(r1Lp + ((i >> 3) * 7 + k) * 512);
      else       a = (i < 8) ? r1k7a : r1k7b;
      if (i < 8) ar0 = MFMA(a, Bh[k], ar0);
      else       ar1 = MFMA(a, Bh[k], ar1);
    }
    bf16x8 pob[8];
    #pragma unroll
    for (int p = 0; p < 8; ++p) pob[p] = *(const bf16x8*)(po_p + p * 512);
    {
      int tn = (t + 1 < TT) ? t + 1 : TT - 1;
      const float* xp = xbase + (size_t)tn * NB * 64;
      xr0 = *(const f32x4*)(xp);      xr1 = *(const f32x4*)(xp + 4);
      xr2 = *(const f32x4*)(xp + 32); xr3 = *(const f32x4*)(xp + 36);
    }
    pack2(uB, wv, lane, am0, am1);
    barrier_lds();  // B2

    #pragma unroll
    for (int p = 0; p < 8; ++p) hpb[p] = *(const bf16x8*)(hp_p + p * 512);
    bf16x8 Bu[8];
    #pragma unroll
    for (int kt = 0; kt < 8; ++kt)
      Bu[kt] = *(const bf16x8*)(uB + kt * 512 + lane * 8);
    {
      float p = 0.f;
      #pragma unroll
      for (int r = 0; r < 4; ++r)
        p += fmaxf(ar0[r], 0.f) * w2a[r] + fmaxf(ar1[r], 0.f) * w2b[r];
      p += __shfl_xor(p, 16, 64);
      p += __shfl_xor(p, 32, 64);
      if (lane < 16) outp[wv * 16 + lane] = p;
    }
    f32x4 ap0 = BIAS(3, mt0), ap1 = BIAS(3, mt0 + 1);
    #pragma unroll
    for (int i = 0; i < 16; ++i) {
      bf16x8 a = pob[i & 7];
      if (i < 8) ap0 = MFMA(a, Bu[i & 7], ap0);
      else       ap1 = MFMA(a, Bu[i & 7], ap1);
      if (i + 8 < 16) pob[i & 7] = *(const bf16x8*)(po_p + (i + 8) * 512);
    }
    pack2(hB, wv, lane, ap0, ap1);
    barrier_lds();  // B3
  }

  if (tid < 16) {
    float s = br2v;
    #pragma unroll
    for (int w = 0; w < 8; ++w) s += outp[w * 16 + tid];
    out[(size_t)(TT - 2) * NB + n0 + tid] = s;
  }
  barrier_lds();

  {
    bf16x8 Bh[8];
    #pragma unroll
    for (int kt = 0; kt < 8; ++kt)
      Bh[kt] = *(const bf16x8*)(hB + kt * 512 + lane * 8);
    f32x4 ar0 = BIAS(4, mt0), ar1 = BIAS(4, mt0 + 1);
    bf16x8 r1b[8];
    #pragma unroll
    for (int p = 0; p < 8; ++p) r1b[p] = *(const bf16x8*)(r1_p + p * 512);
    #pragma unroll
    for (int i = 0; i < 16; ++i) {
      bf16x8 a = r1b[i & 7];
      if (i < 8) ar0 = MFMA(a, Bh[i & 7], ar0);
      else       ar1 = MFMA(a, Bh[i & 7], ar1);
      if (i + 8 < 16) r1b[i & 7] = *(const bf16x8*)(r1_p + (i + 8) * 512);
    }
    float p = 0.f;
    #pragma unroll
    for (int r = 0; r < 4; ++r)
      p += fmaxf(ar0[r], 0.f) * w2a[r] + fmaxf(ar1[r], 0.f) * w2b[r];
    p += __shfl_xor(p, 16, 64);
    p += __shfl_xor(p, 32, 64);
    if (lane < 16) outp[wv * 16 + lane] = p;
    barrier_lds();
    if (tid < 16) {
      float s = br2v;
      #pragma unroll
      for (int w = 0; w < 8; ++w) s += outp[w * 16 + tid];
      out[(size_t)(TT - 1) * NB + n0 + tid] = s;
    }
  }
}

extern "C" void kernel_launch(void* const* d_in, const int* in_sizes, int n_in,
                              void* d_out, int out_size, void* d_ws, size_t ws_size,
                              hipStream_t stream) {
  const float* x      = (const float*)d_in[0];
  const float* Whp    = (const float*)d_in[1];
  const float* bhp    = (const float*)d_in[2];
  const float* Wcp    = (const float*)d_in[3];
  const float* bcp    = (const float*)d_in[4];
  const float* Wm     = (const float*)d_in[5];
  const float* bm     = (const float*)d_in[6];
  const float* Whpost = (const float*)d_in[7];
  const float* bhpost = (const float*)d_in[8];
  const float* Wr1    = (const float*)d_in[9];
  const float* br1    = (const float*)d_in[10];
  const float* Wr2    = (const float*)d_in[11];
  const float* br2    = (const float*)d_in[12];
  __bf16* wsp = (__bf16*)d_ws;
  float*  out = (float*)d_out;

  if (ws_size < (size_t)TOT * sizeof(__bf16)) return;

  pack_weights<<<(TOT + 255) / 256, 256, 0, stream>>>(Whp, Wm, Wcp, Whpost, Wr1, wsp);

  const size_t G_BYTES = (size_t)TT * G_STEP_FLOATS * sizeof(float);
  if (ws_size >= (size_t)G_OFF_BYTES + G_BYTES) {
    float* gws = (float*)((char*)d_ws + G_OFF_BYTES);
    gprep<<<TT * 64, 64, 0, stream>>>(x, wsp, bcp, bm, gws);
    rnn_seq_lean<<<64, 512, 0, stream>>>(wsp, gws, bhp, bcp, bm, bhpost, br1,
                                         Wr2, br2, out);
  } else {
    rnn_seq<<<64, 512, 0, stream>>>(x, wsp, bhp, bcp, bm, bhpost, br1, Wr2,
                                    br2, out);
  }
}

// Round 4
// 2832.384 us; speedup vs baseline: 2.1698x; 2.0195x over previous
//
#include <hip/hip_runtime.h>
#include <hip/hip_bf16.h>

#define TT 512
#define NB 1024

typedef float f32x4 __attribute__((ext_vector_type(4)));
typedef __bf16 bf16x8 __attribute__((ext_vector_type(8)));

// ---- workspace layout (bf16 elems). All matrices stored as A-fragments for
// the TRANSPOSED GEMM  C^T[feature][batch] = W^T @ act^T :
//   frag(mt, kt, lane, j) at ((mt*KT + kt)*512 + lane*8 + j)
//   value = W[kappa][16*mt + (lane&15)]
#define OFF_HP 0
#define OFF_CP 65536
#define OFF_M  81920
#define OFF_PO 212992
#define OFF_R1 278528
#define TOT    344064

// h-history (variant A): hist[((t*64+blk)*8+wv)*512 + lane*8 + j], bf16.
#define H_OFF_BYTES (1u << 20)
#define H_ELEMS ((size_t)TT * 64 * 8 * 512)

// Force true register residency: the value's def becomes this asm, so the
// compiler cannot rematerialize it from memory inside the loop.
#define KEEP(v) asm volatile("" : "+v"(v))

__device__ __forceinline__ bf16x8 as_bf(const f32x4 v) {
  union U { f32x4 f; bf16x8 b; } u; u.f = v; return u.b;
}

__global__ __launch_bounds__(256) void pack_weights(
    const float* __restrict__ Whp, const float* __restrict__ Wm,
    const float* __restrict__ Wcp, const float* __restrict__ Whpost,
    const float* __restrict__ Wr1, __bf16* __restrict__ wsp) {
  int id = blockIdx.x * 256 + threadIdx.x;
  if (id >= TOT) return;
  int j = id & 7, lane = (id >> 3) & 63;
  int lq = lane >> 4, l15 = lane & 15;
  int rel, KT; const float* W; bool perm = true;
  if (id < OFF_CP)      { rel = id;          KT = 8;  W = Whp; }
  else if (id < OFF_M)  { rel = id - OFF_CP; KT = 2;  W = Wcp; perm = false; }
  else if (id < OFF_PO) { rel = id - OFF_M;  KT = 16; W = Wm; }
  else if (id < OFF_R1) { rel = id - OFF_PO; KT = 8;  W = Whpost; }
  else                  { rel = id - OFF_R1; KT = 8;  W = Wr1; }
  int ktm = rel >> 9;
  int kt = ktm % KT, mt = ktm / KT;
  int phi = 16 * mt + l15;
  int kk;
  if (perm) {
    int kb = (kt >= 8) ? kt - 8 : kt;          // only mesh has kt>=8
    kk = 32 * kb + 16 * (j >> 2) + 4 * lq + (j & 3);
    if (kt >= 8) kk += 256;                    // cp half of the concat
  } else {
    kk = 32 * kt + 8 * lq + j;
  }
  wsp[id] = (__bf16)W[kk * 256 + phi];
}

__device__ __forceinline__ float tanh_fast(float x) {
  float t = __expf(2.0f * x);
  return 1.0f - __fdividef(2.0f, t + 1.0f);
}

#define MFMA(a, b, c) __builtin_amdgcn_mfma_f32_16x16x32_bf16((a), (b), (c), 0, 0, 0)

// tanh + pack this wave's two accumulators into ONE B-fragment (kt = wv).
__device__ __forceinline__ bf16x8 pack2(__bf16* region, int wv, int lane,
                                        const f32x4& a0, const f32x4& a1) {
  bf16x8 f;
  #pragma unroll
  for (int r = 0; r < 4; ++r) {
    f[r]     = (__bf16)tanh_fast(a0[r]);
    f[4 + r] = (__bf16)tanh_fast(a1[r]);
  }
  *(bf16x8*)(region + wv * 512 + lane * 8) = f;
  return f;
}

// Raw barrier: make LDS writes visible (lgkmcnt only) WITHOUT draining vmcnt.
__device__ __forceinline__ void barrier_lds() {
  asm volatile("s_waitcnt lgkmcnt(0)" ::: "memory");
  __builtin_amdgcn_s_barrier();
  asm volatile("" ::: "memory");
}

// ---------------------------------------------------------------------------
// Variant A sequential kernel: no out-head in the loop (h stored to history),
// hp + mesh-hp weights FORCED register-resident (128 VGPR), mesh-cp kt<15 in
// LDS, only po/cp/k15 streamed from L2 (~180 KB/step vs 573).
// ---------------------------------------------------------------------------
__global__ __launch_bounds__(512)
__attribute__((amdgpu_waves_per_eu(2, 2)))
void rnn_seq_a(
    const float* __restrict__ x, const __bf16* __restrict__ wsp,
    __bf16* __restrict__ hist,
    const float* __restrict__ bhp, const float* __restrict__ bcp,
    const float* __restrict__ bm, const float* __restrict__ bhpost) {
  __shared__ __align__(16) __bf16 hB[8 * 512];       // h state as B-frags (8K)
  __shared__ __align__(16) __bf16 mB[16 * 512];      // [hpB | cpB] (16K)
  __shared__ __align__(16) __bf16 uB[8 * 512];       // mesh output (8K)
  __shared__ __align__(16) __bf16 wmcL[112 * 512];   // mesh cp-half kt 8..14 (112K)
  __shared__ float lb[4 * 256];                      // bhp,bcp,bm,bhpost (4K)

  const int tid  = threadIdx.x;
  const int wv   = tid >> 6;
  const int lane = tid & 63;
  const int lq   = lane >> 4, l15 = lane & 15;
  const int n0   = blockIdx.x * 16;
  const int mt0  = 2 * wv;

  if (tid < 256) {
    lb[0 * 256 + tid] = bhp[tid];
    lb[1 * 256 + tid] = bcp[tid];
    lb[2 * 256 + tid] = bm[tid];
    lb[3 * 256 + tid] = bhpost[tid];
  }
  for (int i = tid; i < 8 * 512; i += 512) hB[i] = (__bf16)0.0f;

  // one-time: cache mesh cp-half frags (kt 8..14 of every mt) in LDS.
  // LDS frag (mt*7 + c) <- Wm frag (mt*16 + 8 + c), c = 0..6.
  for (int v = tid; v < 112 * 64; v += 512) {
    int frag = v >> 6, lp = v & 63;
    int mt = frag / 7, c = frag - mt * 7;
    ((bf16x8*)wmcL)[v] =
        *(const bf16x8*)(wsp + OFF_M + (size_t)(mt * 16 + 8 + c) * 512 + lp * 8);
  }

  #define BIAS(a, m) (*(const f32x4*)(lb + (a) * 256 + (m) * 16 + 4 * lq))

  // ---- FORCED register-resident weights: hp (16 frags) + mesh-hp (16) ----
  f32x4 hpw[16], wmh[16];
  {
    const __bf16* hp0 = wsp + OFF_HP + (size_t)(mt0 * 8) * 512 + lane * 8;
    const __bf16* mp  = wsp + OFF_M + (size_t)(mt0 * 16) * 512 + lane * 8;
    #pragma unroll
    for (int i = 0; i < 16; ++i) hpw[i] = *(const f32x4*)(hp0 + i * 512);
    #pragma unroll
    for (int kt = 0; kt < 8; ++kt) {
      wmh[kt]     = *(const f32x4*)(mp + kt * 512);          // (mt0,   kt)
      wmh[8 + kt] = *(const f32x4*)(mp + (16 + kt) * 512);   // (mt0+1, kt)
    }
  }
  #pragma unroll
  for (int i = 0; i < 16; ++i) { KEEP(hpw[i]); KEEP(wmh[i]); }

  const __bf16* cp_p   = wsp + OFF_CP + (size_t)(mt0 * 2) * 512 + lane * 8;
  const __bf16* po_p   = wsp + OFF_PO + (size_t)(mt0 * 8) * 512 + lane * 8;
  const __bf16* wmk15a = wsp + OFF_M + (size_t)(mt0 * 16 + 15) * 512 + lane * 8;
  const __bf16* wmk15b = wsp + OFF_M + (size_t)((mt0 + 1) * 16 + 15) * 512 + lane * 8;
  const __bf16* wc0 = wmcL + (size_t)(mt0 * 7) * 512 + lane * 8;
  const __bf16* wc1 = wmcL + (size_t)((mt0 + 1) * 7) * 512 + lane * 8;
  __bf16* hst = hist + (size_t)(blockIdx.x * 8 + wv) * 512 + lane * 8;

  __syncthreads();

  const float* xbase = x + (size_t)(n0 + l15) * 64 + 8 * lq;
  f32x4 xr0 = *(const f32x4*)(xbase);
  f32x4 xr1 = *(const f32x4*)(xbase + 4);
  f32x4 xr2 = *(const f32x4*)(xbase + 32);
  f32x4 xr3 = *(const f32x4*)(xbase + 36);

  for (int t = 0; t < TT; ++t) {
    bf16x8 Bx0, Bx1;
    #pragma unroll
    for (int j = 0; j < 4; ++j) {
      Bx0[j] = (__bf16)xr0[j]; Bx0[4 + j] = (__bf16)xr1[j];
      Bx1[j] = (__bf16)xr2[j]; Bx1[4 + j] = (__bf16)xr3[j];
    }

    // ---- stage 1: hp = h@Whp + bhp (weights in regs!) ; cp = x@Wcp + bcp --
    bf16x8 cpb[4];
    #pragma unroll
    for (int p = 0; p < 4; ++p) cpb[p] = *(const bf16x8*)(cp_p + p * 512);
    bf16x8 wk15a = *(const bf16x8*)(wmk15a);
    bf16x8 wk15b = *(const bf16x8*)(wmk15b);
    bf16x8 Bh[8];
    #pragma unroll
    for (int kt = 0; kt < 8; ++kt)
      Bh[kt] = *(const bf16x8*)(hB + kt * 512 + lane * 8);

    f32x4 ah0 = BIAS(0, mt0), ah1 = BIAS(0, mt0 + 1);
    #pragma unroll
    for (int i = 0; i < 16; ++i) {
      bf16x8 a = as_bf(hpw[i]);
      if (i < 8) ah0 = MFMA(a, Bh[i & 7], ah0);
      else       ah1 = MFMA(a, Bh[i & 7], ah1);
    }
    f32x4 ac0 = BIAS(1, mt0), ac1 = BIAS(1, mt0 + 1);
    ac0 = MFMA(cpb[0], Bx0, ac0); ac0 = MFMA(cpb[1], Bx1, ac0);
    ac1 = MFMA(cpb[2], Bx0, ac1); ac1 = MFMA(cpb[3], Bx1, ac1);

    pack2(mB,           wv, lane, ah0, ah1);
    pack2(mB + 8 * 512, wv, lane, ac0, ac1);
    barrier_lds();  // B1

    // ---- stage 2: u = cat@Wm + bm  (hp-half in regs, cp-half LDS + k15) ---
    f32x4 am0 = BIAS(2, mt0), am1 = BIAS(2, mt0 + 1);
    #pragma unroll
    for (int i = 0; i < 16; ++i) {
      bf16x8 Bm = *(const bf16x8*)(mB + i * 512 + lane * 8);
      bf16x8 w0, w1;
      if (i < 8)       { w0 = as_bf(wmh[i]); w1 = as_bf(wmh[8 + i]); }
      else if (i < 15) { w0 = *(const bf16x8*)(wc0 + (i - 8) * 512);
                         w1 = *(const bf16x8*)(wc1 + (i - 8) * 512); }
      else             { w0 = wk15a; w1 = wk15b; }
      am0 = MFMA(w0, Bm, am0);
      am1 = MFMA(w1, Bm, am1);
    }
    // prefetch: po first half + next step's x (fly across B2/B3, no drain)
    bf16x8 pob[8];
    #pragma unroll
    for (int p = 0; p < 8; ++p) pob[p] = *(const bf16x8*)(po_p + p * 512);
    {
      int tn = (t + 1 < TT) ? t + 1 : TT - 1;
      const float* xp = xbase + (size_t)tn * NB * 64;
      xr0 = *(const f32x4*)(xp);      xr1 = *(const f32x4*)(xp + 4);
      xr2 = *(const f32x4*)(xp + 32); xr3 = *(const f32x4*)(xp + 36);
    }
    pack2(uB, wv, lane, am0, am1);
    barrier_lds();  // B2

    // ---- stage 3: h = tanh(u @ Whpost + bhpost) ; store h to history ------
    bf16x8 Bu[8];
    #pragma unroll
    for (int kt = 0; kt < 8; ++kt)
      Bu[kt] = *(const bf16x8*)(uB + kt * 512 + lane * 8);
    f32x4 ap0 = BIAS(3, mt0), ap1 = BIAS(3, mt0 + 1);
    #pragma unroll
    for (int i = 0; i < 16; ++i) {
      bf16x8 a = pob[i & 7];
      if (i < 8) ap0 = MFMA(a, Bu[i & 7], ap0);
      else       ap1 = MFMA(a, Bu[i & 7], ap1);
      if (i + 8 < 16) pob[i & 7] = *(const bf16x8*)(po_p + (i + 8) * 512);
    }
    bf16x8 f = pack2(hB, wv, lane, ap0, ap1);
    *(bf16x8*)(hst + (size_t)t * (64 * 8 * 512)) = f;   // fire-and-forget
    barrier_lds();  // B3
  }
  #undef BIAS
}

// ---------------------------------------------------------------------------
// Variant A head: out[t] = relu(h(t)@Wr1 + br1)@Wr2 + br2, fully parallel.
// Same frag data + same MFMA/reduction order as the in-loop head -> identical.
// ---------------------------------------------------------------------------
__global__ __launch_bounds__(512) void head_out(
    const __bf16* __restrict__ wsp, const __bf16* __restrict__ hist,
    const float* __restrict__ br1, const float* __restrict__ Wr2,
    const float* __restrict__ br2, float* __restrict__ out) {
  __shared__ float outp[128];
  const int tid  = threadIdx.x;
  const int wv   = tid >> 6;
  const int lane = tid & 63;
  const int lq   = lane >> 4;
  const int t    = blockIdx.x;
  const int mt0  = 2 * wv;

  f32x4 r1w[16];
  {
    const __bf16* r1p = wsp + OFF_R1 + (size_t)(mt0 * 8) * 512 + lane * 8;
    #pragma unroll
    for (int i = 0; i < 16; ++i) r1w[i] = *(const f32x4*)(r1p + i * 512);
  }
  #pragma unroll
  for (int i = 0; i < 16; ++i) KEEP(r1w[i]);

  const f32x4 w2a = *(const f32x4*)(Wr2 + mt0 * 16 + 4 * lq);
  const f32x4 w2b = *(const f32x4*)(Wr2 + (mt0 + 1) * 16 + 4 * lq);
  const f32x4 b0  = *(const f32x4*)(br1 + mt0 * 16 + 4 * lq);
  const f32x4 b1  = *(const f32x4*)(br1 + (mt0 + 1) * 16 + 4 * lq);
  const float br2v = br2[0];

  for (int nb = 0; nb < 64; ++nb) {
    const __bf16* hp = hist + (size_t)((t * 64 + nb) * 8) * 512 + lane * 8;
    bf16x8 Bh[8];
    #pragma unroll
    for (int k = 0; k < 8; ++k) Bh[k] = *(const bf16x8*)(hp + k * 512);
    f32x4 ar0 = b0, ar1 = b1;
    #pragma unroll
    for (int i = 0; i < 16; ++i) {
      if (i < 8) ar0 = MFMA(as_bf(r1w[i]), Bh[i], ar0);
      else       ar1 = MFMA(as_bf(r1w[i]), Bh[i - 8], ar1);
    }
    float p = 0.f;
    #pragma unroll
    for (int r = 0; r < 4; ++r)
      p += fmaxf(ar0[r], 0.f) * w2a[r] + fmaxf(ar1[r], 0.f) * w2b[r];
    p += __shfl_xor(p, 16, 64);
    p += __shfl_xor(p, 32, 64);
    if (lane < 16) outp[wv * 16 + lane] = p;
    __syncthreads();
    if (tid < 16) {
      float s = br2v;
      #pragma unroll
      for (int w = 0; w < 8; ++w) s += outp[w * 16 + tid];
      out[(size_t)t * NB + nb * 16 + tid] = s;
    }
    __syncthreads();
  }
}

// ---------------------------------------------------------------------------
// Variant B (fallback, small ws): R3 kernel + forced wm0 residency (64 VGPR).
// ---------------------------------------------------------------------------
__global__ __launch_bounds__(512)
__attribute__((amdgpu_waves_per_eu(2, 2)))
void rnn_seq(
    const float* __restrict__ x, const __bf16* __restrict__ wsp,
    const float* __restrict__ bhp, const float* __restrict__ bcp,
    const float* __restrict__ bm, const float* __restrict__ bhpost,
    const float* __restrict__ br1, const float* __restrict__ Wr2,
    const float* __restrict__ br2, float* __restrict__ out) {
  __shared__ __align__(16) __bf16 hB[8 * 512];
  __shared__ __align__(16) __bf16 mB[16 * 512];
  __shared__ __align__(16) __bf16 uB[8 * 512];
  __shared__ __align__(16) __bf16 r1L[112 * 512];
  __shared__ float lb[5 * 256];
  __shared__ float outp[128];

  const int tid  = threadIdx.x;
  const int wv   = tid >> 6;
  const int lane = tid & 63;
  const int lq   = lane >> 4, l15 = lane & 15;
  const int n0   = blockIdx.x * 16;
  const int mt0  = 2 * wv;

  if (tid < 256) {
    lb[0 * 256 + tid] = bhp[tid];
    lb[1 * 256 + tid] = bcp[tid];
    lb[2 * 256 + tid] = bm[tid];
    lb[3 * 256 + tid] = bhpost[tid];
    lb[4 * 256 + tid] = br1[tid];
  }
  for (int i = tid; i < 8 * 512; i += 512) hB[i] = (__bf16)0.0f;

  for (int v = tid; v < 112 * 64; v += 512) {
    int frag = v >> 6, lp = v & 63;
    int mt = frag / 7, kt = frag - mt * 7;
    ((bf16x8*)r1L)[v] =
        *(const bf16x8*)(wsp + OFF_R1 + (size_t)(mt * 8 + kt) * 512 + lp * 8);
  }
  const float br2v = br2[0];

  #define BIAS(a, m) (*(const f32x4*)(lb + (a) * 256 + (m) * 16 + 4 * lq))
  const f32x4 w2a = *(const f32x4*)(Wr2 + mt0 * 16 + 4 * lq);
  const f32x4 w2b = *(const f32x4*)(Wr2 + (mt0 + 1) * 16 + 4 * lq);

  // am0-half of mesh weights FORCED resident; am1-half streamed as before.
  f32x4 wm0f[16]; bf16x8 wm1[16];
  {
    const __bf16* mp = wsp + OFF_M + (size_t)(mt0 * 16) * 512 + lane * 8;
    #pragma unroll
    for (int kt = 0; kt < 16; ++kt) {
      wm0f[kt] = *(const f32x4*)(mp + kt * 512);
      wm1[kt]  = *(const bf16x8*)(mp + (16 + kt) * 512);
    }
  }
  #pragma unroll
  for (int i = 0; i < 16; ++i) KEEP(wm0f[i]);

  const __bf16* hp_p = wsp + OFF_HP + (size_t)(mt0 * 8) * 512 + lane * 8;
  const __bf16* r1_p = wsp + OFF_R1 + (size_t)(mt0 * 8) * 512 + lane * 8;
  const __bf16* cp_p = wsp + OFF_CP + (size_t)(mt0 * 2) * 512 + lane * 8;
  const __bf16* po_p = wsp + OFF_PO + (size_t)(mt0 * 8) * 512 + lane * 8;
  const __bf16* r1Lp = r1L + (size_t)(mt0 * 7) * 512 + lane * 8;

  __syncthreads();

  const float* xbase = x + (size_t)(n0 + l15) * 64 + 8 * lq;
  f32x4 xr0 = *(const f32x4*)(xbase);
  f32x4 xr1 = *(const f32x4*)(xbase + 4);
  f32x4 xr2 = *(const f32x4*)(xbase + 32);
  f32x4 xr3 = *(const f32x4*)(xbase + 36);

  bf16x8 hpb[8];
  #pragma unroll
  for (int p = 0; p < 8; ++p) hpb[p] = *(const bf16x8*)(hp_p + p * 512);

  for (int t = 0; t < TT; ++t) {
    if (t >= 2 && tid < 16) {
      float s = br2v;
      #pragma unroll
      for (int w = 0; w < 8; ++w) s += outp[w * 16 + tid];
      out[(size_t)(t - 2) * NB + n0 + tid] = s;
    }

    bf16x8 Bx0, Bx1;
    #pragma unroll
    for (int j = 0; j < 4; ++j) {
      Bx0[j] = (__bf16)xr0[j]; Bx0[4 + j] = (__bf16)xr1[j];
      Bx1[j] = (__bf16)xr2[j]; Bx1[4 + j] = (__bf16)xr3[j];
    }

    bf16x8 cpb[4];
    #pragma unroll
    for (int p = 0; p < 4; ++p) cpb[p] = *(const bf16x8*)(cp_p + p * 512);
    bf16x8 r1k7a = *(const bf16x8*)(r1_p + 7 * 512);
    bf16x8 r1k7b = *(const bf16x8*)(r1_p + 15 * 512);
    bf16x8 Bh[8];
    #pragma unroll
    for (int kt = 0; kt < 8; ++kt)
      Bh[kt] = *(const bf16x8*)(hB + kt * 512 + lane * 8);

    f32x4 ah0 = BIAS(0, mt0), ah1 = BIAS(0, mt0 + 1);
    #pragma unroll
    for (int i = 0; i < 16; ++i) {
      bf16x8 a = hpb[i & 7];
      if (i < 8) ah0 = MFMA(a, Bh[i & 7], ah0);
      else       ah1 = MFMA(a, Bh[i & 7], ah1);
      if (i + 8 < 16) hpb[i & 7] = *(const bf16x8*)(hp_p + (i + 8) * 512);
    }
    f32x4 ac0 = BIAS(1, mt0), ac1 = BIAS(1, mt0 + 1);
    ac0 = MFMA(cpb[0], Bx0, ac0); ac0 = MFMA(cpb[1], Bx1, ac0);
    ac1 = MFMA(cpb[2], Bx0, ac1); ac1 = MFMA(cpb[3], Bx1, ac1);

    pack2(mB,           wv, lane, ah0, ah1);
    pack2(mB + 8 * 512, wv, lane, ac0, ac1);
    barrier_lds();  // B1

    f32x4 am0 = BIAS(2, mt0), am1 = BIAS(2, mt0 + 1);
    f32x4 ar0 = BIAS(4, mt0), ar1 = BIAS(4, mt0 + 1);
    #pragma unroll
    for (int i = 0; i < 16; ++i) {
      bf16x8 Bm = *(const bf16x8*)(mB + i * 512 + lane * 8);
      am0 = MFMA(as_bf(wm0f[i]), Bm, am0);
      am1 = MFMA(wm1[i], Bm, am1);
      int k = i & 7;
      bf16x8 a;
      if (k < 7) a = *(const bf16x8*)(r1Lp + ((i >> 3) * 7 + k) * 512);
      else       a = (i < 8) ? r1k7a : r1k7b;
      if (i < 8) ar0 = MFMA(a, Bh[k], ar0);
      else       ar1 = MFMA(a, Bh[k], ar1);
    }
    bf16x8 pob[8];
    #pragma unroll
    for (int p = 0; p < 8; ++p) pob[p] = *(const bf16x8*)(po_p + p * 512);
    {
      int tn = (t + 1 < TT) ? t + 1 : TT - 1;
      const float* xp = xbase + (size_t)tn * NB * 64;
      xr0 = *(const f32x4*)(xp);      xr1 = *(const f32x4*)(xp + 4);
      xr2 = *(const f32x4*)(xp + 32); xr3 = *(const f32x4*)(xp + 36);
    }
    pack2(uB, wv, lane, am0, am1);
    barrier_lds();  // B2

    #pragma unroll
    for (int p = 0; p < 8; ++p) hpb[p] = *(const bf16x8*)(hp_p + p * 512);
    bf16x8 Bu[8];
    #pragma unroll
    for (int kt = 0; kt < 8; ++kt)
      Bu[kt] = *(const bf16x8*)(uB + kt * 512 + lane * 8);
    {
      float p = 0.f;
      #pragma unroll
      for (int r = 0; r < 4; ++r)
        p += fmaxf(ar0[r], 0.f) * w2a[r] + fmaxf(ar1[r], 0.f) * w2b[r];
      p += __shfl_xor(p, 16, 64);
      p += __shfl_xor(p, 32, 64);
      if (lane < 16) outp[wv * 16 + lane] = p;
    }
    f32x4 ap0 = BIAS(3, mt0), ap1 = BIAS(3, mt0 + 1);
    #pragma unroll
    for (int i = 0; i < 16; ++i) {
      bf16x8 a = pob[i & 7];
      if (i < 8) ap0 = MFMA(a, Bu[i & 7], ap0);
      else       ap1 = MFMA(a, Bu[i & 7], ap1);
      if (i + 8 < 16) pob[i & 7] = *(const bf16x8*)(po_p + (i + 8) * 512);
    }
    pack2(hB, wv, lane, ap0, ap1);
    barrier_lds();  // B3
  }

  if (tid < 16) {
    float s = br2v;
    #pragma unroll
    for (int w = 0; w < 8; ++w) s += outp[w * 16 + tid];
    out[(size_t)(TT - 2) * NB + n0 + tid] = s;
  }
  barrier_lds();

  {
    bf16x8 Bh[8];
    #pragma unroll
    for (int kt = 0; kt < 8; ++kt)
      Bh[kt] = *(const bf16x8*)(hB + kt * 512 + lane * 8);
    f32x4 ar0 = BIAS(4, mt0), ar1 = BIAS(4, mt0 + 1);
    bf16x8 r1b[8];
    #pragma unroll
    for (int p = 0; p < 8; ++p) r1b[p] = *(const bf16x8*)(r1_p + p * 512);
    #pragma unroll
    for (int i = 0; i < 16; ++i) {
      bf16x8 a = r1b[i & 7];
      if (i < 8) ar0 = MFMA(a, Bh[i & 7], ar0);
      else       ar1 = MFMA(a, Bh[i & 7], ar1);
      if (i + 8 < 16) r1b[i & 7] = *(const bf16x8*)(r1_p + (i + 8) * 512);
    }
    float p = 0.f;
    #pragma unroll
    for (int r = 0; r < 4; ++r)
      p += fmaxf(ar0[r], 0.f) * w2a[r] + fmaxf(ar1[r], 0.f) * w2b[r];
    p += __shfl_xor(p, 16, 64);
    p += __shfl_xor(p, 32, 64);
    if (lane < 16) outp[wv * 16 + lane] = p;
    barrier_lds();
    if (tid < 16) {
      float s = br2v;
      #pragma unroll
      for (int w = 0; w < 8; ++w) s += outp[w * 16 + tid];
      out[(size_t)(TT - 1) * NB + n0 + tid] = s;
    }
  }
  #undef BIAS
}

extern "C" void kernel_launch(void* const* d_in, const int* in_sizes, int n_in,
                              void* d_out, int out_size, void* d_ws, size_t ws_size,
                              hipStream_t stream) {
  const float* x      = (const float*)d_in[0];
  const float* Whp    = (const float*)d_in[1];
  const float* bhp    = (const float*)d_in[2];
  const float* Wcp    = (const float*)d_in[3];
  const float* bcp    = (const float*)d_in[4];
  const float* Wm     = (const float*)d_in[5];
  const float* bm     = (const float*)d_in[6];
  const float* Whpost = (const float*)d_in[7];
  const float* bhpost = (const float*)d_in[8];
  const float* Wr1    = (const float*)d_in[9];
  const float* br1    = (const float*)d_in[10];
  const float* Wr2    = (const float*)d_in[11];
  const float* br2    = (const float*)d_in[12];
  __bf16* wsp = (__bf16*)d_ws;
  float*  out = (float*)d_out;

  if (ws_size < (size_t)TOT * sizeof(__bf16)) return;

  pack_weights<<<(TOT + 255) / 256, 256, 0, stream>>>(Whp, Wm, Wcp, Whpost, Wr1, wsp);

  const size_t H_BYTES = H_ELEMS * sizeof(__bf16);   // 268 MB
  if (ws_size >= (size_t)H_OFF_BYTES + H_BYTES) {
    __bf16* hist = (__bf16*)((char*)d_ws + H_OFF_BYTES);
    rnn_seq_a<<<64, 512, 0, stream>>>(x, wsp, hist, bhp, bcp, bm, bhpost);
    head_out<<<TT, 512, 0, stream>>>(wsp, hist, br1, Wr2, br2, out);
  } else {
    rnn_seq<<<64, 512, 0, stream>>>(x, wsp, bhp, bcp, bm, bhpost, br1, Wr2,
                                    br2, out);
  }
}